// Round 1
// baseline (229.043 us; speedup 1.0000x reference)
//
#include <hip/hip_runtime.h>
#include <hip/hip_bf16.h>

#define S_LEN 2048
#define NHEAD 12
#define NBH 48          // B*H
#define DMODEL 768
#define BR 128          // q rows per block (4 waves x 32)
#define BC 128          // keys per K-tile

typedef __bf16 bf16x8 __attribute__((ext_vector_type(8)));
typedef float f32x4  __attribute__((ext_vector_type(4)));
typedef float f32x16 __attribute__((ext_vector_type(16)));

union B8U { uint4 u; bf16x8 b; };

__device__ __forceinline__ unsigned bf16rne(float f) {
  unsigned u = __float_as_uint(f);
  return (u + 0x7fffu + ((u >> 16) & 1u)) >> 16;
}

// ============ Kernel 0: weights fp32 -> bf16, once (294 KB total) ============
__global__ __launch_bounds__(256)
void w_cvt(const float* __restrict__ Wq, const float* __restrict__ Wk,
           const float* __restrict__ Wv, unsigned short* __restrict__ Wb) {
  int idx = blockIdx.x * 256 + threadIdx.x;        // 36864 float4s total
  int mat = idx / 12288;
  int off = idx - mat * 12288;
  const float* src = (mat == 0) ? Wq : (mat == 1) ? Wk : Wv;
  float4 v = ((const float4*)src)[off];
  ushort4 o;
  o.x = (unsigned short)bf16rne(v.x);
  o.y = (unsigned short)bf16rne(v.y);
  o.z = (unsigned short)bf16rne(v.z);
  o.w = (unsigned short)bf16rne(v.w);
  ((ushort4*)(Wb + (size_t)mat * 49152))[off] = o;
}

// ================= Kernel 1: per-head QKV projection (MFMA) =================
// All 6 acc tiles computed first (W-loads overlap repack), then each output is
// repacked through LDS and stored with fully-coalesced uint4 writes (direct
// ushort4 scatter stores cost ~17 us PER matrix in R3/R4).
// 1D grid, bh = id%48: qkv's outputs land in the SAME XCD L2 flash reads from.
__global__ __launch_bounds__(256, 3)
void qkv_proj(const float* __restrict__ seq,
              const unsigned short* __restrict__ Wb,
              const float* __restrict__ bq, const float* __restrict__ bk,
              const float* __restrict__ bv,
              unsigned short* __restrict__ Qp, unsigned short* __restrict__ Kp,
              unsigned short* __restrict__ VTp) {
  __shared__ __align__(16) unsigned short xs[128][72];   // 18432 B, reused as Rt/Vt

  const int tid  = threadIdx.x;
  const int lane = tid & 63;
  const int wave = tid >> 6;
  const int L    = lane >> 5;
  const int l31  = lane & 31;
  const int bh    = blockIdx.x % NBH;    // XCD pin matches flash (id%8 == bh%8)
  const int stile = blockIdx.x / NBH;    // 0..15
  const int b = bh / NHEAD, h = bh % NHEAD;
  const int s0 = stile * 128;

  // ---- stage x tile [128][64] fp32 -> bf16(RNE) LDS, coalesced ----
#pragma unroll
  for (int p = 0; p < 8; ++p) {
    int f = tid + p * 256;
    int row = f >> 4, c4 = f & 15;
    float4 x = *(const float4*)&seq[((size_t)(b * S_LEN + s0 + row)) * DMODEL + h * 64 + c4 * 4];
    uint2 d;
    d.x = bf16rne(x.x) | (bf16rne(x.y) << 16);
    d.y = bf16rne(x.z) | (bf16rne(x.w) << 16);
    *(uint2*)&xs[row][c4 * 4] = d;
  }
  __syncthreads();

  // x frags: lane holds x[s=wave*32+l31][d=ks*16+L*8 ..+8]
  bf16x8 af[4];
#pragma unroll
  for (int ks = 0; ks < 4; ++ks)
    af[ks] = *(const bf16x8*)&xs[wave * 32 + l31][ks * 16 + L * 8];

  // ---- compute all 6 acc tiles (Q,K: C[e][s]; V: C[s][e]) ----
  f32x16 qacc[2], kacc[2], vacc[2];
#pragma unroll
  for (int nt = 0; nt < 2; ++nt) {
    const int e = nt * 32 + l31;
    bf16x8 wf[4];
#pragma unroll
    for (int i = 0; i < 16; ++i) { qacc[nt][i] = 0.f; kacc[nt][i] = 0.f; vacc[nt][i] = 0.f; }
#pragma unroll
    for (int ks = 0; ks < 4; ++ks)
      wf[ks] = *(const bf16x8*)&Wb[(size_t)h * 4096 + (size_t)e * 64 + ks * 16 + L * 8];
#pragma unroll
    for (int ks = 0; ks < 4; ++ks)
      qacc[nt] = __builtin_amdgcn_mfma_f32_32x32x16_bf16(wf[ks], af[ks], qacc[nt], 0, 0, 0);
#pragma unroll
    for (int ks = 0; ks < 4; ++ks)
      wf[ks] = *(const bf16x8*)&Wb[49152 + (size_t)h * 4096 + (size_t)e * 64 + ks * 16 + L * 8];
#pragma unroll
    for (int ks = 0; ks < 4; ++ks)
      kacc[nt] = __builtin_amdgcn_mfma_f32_32x32x16_bf16(wf[ks], af[ks], kacc[nt], 0, 0, 0);
#pragma unroll
    for (int ks = 0; ks < 4; ++ks)
      wf[ks] = *(const bf16x8*)&Wb[2 * 49152 + (size_t)h * 4096 + (size_t)e * 64 + ks * 16 + L * 8];
#pragma unroll
    for (int ks = 0; ks < 4; ++ks)
      vacc[nt] = __builtin_amdgcn_mfma_f32_32x32x16_bf16(af[ks], wf[ks], vacc[nt], 0, 0, 0);
  }
  __syncthreads();                       // xs (af source) dead for all waves

  const float qs = 0.18033688011112042f; // log2(e)/8 (exp2-domain softmax)

  // ---- Q then K: C[e][s] -> Rt[s][e] in LDS -> coalesced uint4 stores ----
  unsigned short (*Rt)[72] = (unsigned short(*)[72])xs;   // [128 s][72] 18432 B
#pragma unroll
  for (int mat = 0; mat < 2; ++mat) {
    const f32x16* A = (mat == 0) ? qacc : kacc;
    const float* bp0 = (mat == 0) ? bq : bk;
    float sc = (mat == 0) ? qs : 1.0f;
#pragma unroll
    for (int nt = 0; nt < 2; ++nt)
#pragma unroll
      for (int rq = 0; rq < 4; ++rq) {
        int e0 = nt * 32 + 8 * rq + 4 * L;
        const float* bp = bp0 + h * 64 + e0;   // lane-uniform -> scalar loads
        ushort4 pv;
        pv.x = (unsigned short)bf16rne((A[nt][4 * rq + 0] + bp[0]) * sc);
        pv.y = (unsigned short)bf16rne((A[nt][4 * rq + 1] + bp[1]) * sc);
        pv.z = (unsigned short)bf16rne((A[nt][4 * rq + 2] + bp[2]) * sc);
        pv.w = (unsigned short)bf16rne((A[nt][4 * rq + 3] + bp[3]) * sc);
        *(ushort4*)&Rt[wave * 32 + l31][e0] = pv;
      }
    __syncthreads();
    unsigned short* P = (mat == 0) ? Qp : Kp;
#pragma unroll
    for (int p = 0; p < 4; ++p) {
      int f = tid + p * 256;               // 1024 x 16B chunks
      int row = f >> 3, c = f & 7;
      uint4 d = *(const uint4*)&Rt[row][c * 8];
      *(uint4*)&P[((size_t)bh * S_LEN + s0 + row) * 64 + c * 8] = d;
    }
    __syncthreads();                       // LDS reads done before reuse
  }

  // ---- V: C[s][e] -> Vt[e][s] in LDS -> coalesced uint4 stores ----
  unsigned short (*Vt)[136] = (unsigned short(*)[136])xs;  // [64 e][136] 17408 B
#pragma unroll
  for (int nt = 0; nt < 2; ++nt) {
    const int e = nt * 32 + l31;
    float bias = bv[h * 64 + e];
#pragma unroll
    for (int rq = 0; rq < 4; ++rq) {
      ushort4 pv;
      pv.x = (unsigned short)bf16rne(vacc[nt][4 * rq + 0] + bias);
      pv.y = (unsigned short)bf16rne(vacc[nt][4 * rq + 1] + bias);
      pv.z = (unsigned short)bf16rne(vacc[nt][4 * rq + 2] + bias);
      pv.w = (unsigned short)bf16rne(vacc[nt][4 * rq + 3] + bias);
      *(ushort4*)&Vt[e][wave * 32 + 8 * rq + 4 * L] = pv;
    }
  }
  __syncthreads();
#pragma unroll
  for (int p = 0; p < 4; ++p) {
    int f = tid + p * 256;                 // 1024 x 16B chunks
    int row = f >> 4, c = f & 15;
    uint4 d = *(const uint4*)&Vt[row][c * 8];
    *(uint4*)&VTp[((size_t)bh * 64 + row) * S_LEN + s0 + c * 8] = d;
  }
}

// ============ Kernel 2: flash attention, fixed-base softmax ============
// R5 changes (flash only):
//  - permlane32_swap pack: the {u0_lo,u2_lo}/{u0_hi,u2_hi} B-frag build IS
//    v_permlane32_swap_b32 (hi(dst)<->lo(src)); kills 16 ds_bpermute/iter/wave
//    on the LDS pipe (the structurally-busiest pipe) + ~6 cndmask per pack.
//  - in-wave pipeline: S(0,1) -> EPV(0) -> S(2,3) -> EPV(1..3) so S-MFMAs of
//    tiles 2,3 drain under EPV VALU instead of phase-segregating.
//  - s_setprio(1) around MFMA clusters (T5).
//  - block phase stagger: fixed-base softmax = pure sum, K-tile order is free;
//    phase decorrelates the 3 co-resident blocks' barrier convoy.
__global__ __launch_bounds__(256, 3)
void flash_attn(const unsigned short* __restrict__ Qp,
                const unsigned short* __restrict__ Kp,
                const unsigned short* __restrict__ VTp,
                float* __restrict__ out) {
  __shared__ __align__(16) char smem[35840];
  unsigned short (*Ks)[72]  = (unsigned short(*)[72])smem;            // [128][72]
  unsigned short (*Vs)[136] = (unsigned short(*)[136])(smem + 18432); // [64][136]

  const int tid  = threadIdx.x;
  const int wave = tid >> 6;
  const int lane = tid & 63;
  const int L    = lane >> 5;
  const int l31  = lane & 31;
  // XCD pinning: id%8 == bh%8 -> all 16 q-tiles of a bh share one XCD's L2
  const int bh = blockIdx.x % NBH;
  const int qx = blockIdx.x / NBH;
  const int b = bh / NHEAD, h = bh % NHEAD;
  const int q0 = qx * BR;
  // stagger start tile across blocks that may co-reside on a CU
  const int phase = ((blockIdx.x >> 3) & 3) << 2;   // 0,4,8,12

  // Q frags (B-operand): lane holds Q[q=l31][d=ks*16+L*8+j]
  bf16x8 qfrag[4];
  {
    const uint4* Qv = (const uint4*)Qp;
#pragma unroll
    for (int ks = 0; ks < 4; ++ks) {
      B8U t;
      t.u = Qv[((size_t)bh * S_LEN + q0 + wave * 32 + l31) * 8 + ks * 2 + L];
      qfrag[ks] = t.b;
    }
  }

  f32x16 oacc[2];
#pragma unroll
  for (int mt = 0; mt < 2; ++mt)
#pragma unroll
    for (int i = 0; i < 16; ++i) oacc[mt][i] = 0.f;
  float l_run = 0.f;

  const uint4* Kv = (const uint4*)Kp  + (size_t)bh * S_LEN * 8;
  const uint4* Vv = (const uint4*)VTp + (size_t)bh * 64 * 256;

  uint4 kd[4], vd[4];
  {
    const int t00 = phase * BC;
#pragma unroll
    for (int i = 0; i < 4; ++i) {
      int f = tid + i * 256;
      kd[i] = Kv[(size_t)(t00 + (f >> 3)) * 8 + (f & 7)];
      vd[i] = Vv[(size_t)(f >> 4) * 256 + (t00 >> 3) + (f & 15)];
    }
  }

  // EPV: exp2 + bf16-truncate pack + PV-MFMA for one 32-key score tile.
  // l sums the SAME truncated values so rounding bias cancels in p/l.
  auto EPV = [&](const f32x16& sc, int tt) {
    unsigned pk[8];
    float la = 0.f, lb = 0.f;               // split l chain (was 64-deep serial)
#pragma unroll
    for (int p = 0; p < 8; ++p) {
      unsigned u0 = __float_as_uint(__builtin_amdgcn_exp2f(sc[2 * p]));
      unsigned u1 = __float_as_uint(__builtin_amdgcn_exp2f(sc[2 * p + 1]));
      unsigned d = __builtin_amdgcn_perm(u1, u0, 0x07060302);  // {hi16(u1),hi16(u0)}
      pk[p] = d;
      la += __uint_as_float(d << 16);
      lb += __uint_as_float(d & 0xffff0000u);
    }
    l_run += la + lb;
#pragma unroll
    for (int mk = 0; mk < 2; ++mk) {
      const int m = 2 * tt + mk;
      unsigned a0 = pk[4 * mk + 0], a1 = pk[4 * mk + 1];
      unsigned b0 = pk[4 * mk + 2], b1 = pk[4 * mk + 3];
      // hi32lanes(a) <-> lo32lanes(b):  a'={a_lo,b_lo}  b'={a_hi,b_hi}
      asm("v_permlane32_swap_b32 %0, %1" : "+v"(a0), "+v"(b0));
      asm("v_permlane32_swap_b32 %0, %1" : "+v"(a1), "+v"(b1));
      B8U t;
      t.u.x = a0; t.u.y = a1; t.u.z = b0; t.u.w = b1;
      __builtin_amdgcn_s_setprio(1);
#pragma unroll
      for (int mt = 0; mt < 2; ++mt) {
        bf16x8 va = *(const bf16x8*)&Vs[mt * 32 + l31][m * 16 + L * 8];
        oacc[mt] = __builtin_amdgcn_mfma_f32_32x32x16_bf16(va, t.b, oacc[mt], 0, 0, 0);
      }
      __builtin_amdgcn_s_setprio(0);
    }
  };

  for (int i = 0; i < S_LEN / BC; ++i) {
    const int it = (i + phase) & (S_LEN / BC - 1);
    __syncthreads();
#pragma unroll
    for (int j = 0; j < 4; ++j) {
      int f = tid + j * 256;
      *(uint4*)&Ks[f >> 3][(f & 7) * 8]  = kd[j];
      *(uint4*)&Vs[f >> 4][(f & 15) * 8] = vd[j];
    }
    if (i + 1 < S_LEN / BC) {      // next tile's loads: a full iter of latency cover
      int t0n = ((it + 1) & (S_LEN / BC - 1)) * BC;
#pragma unroll
      for (int j = 0; j < 4; ++j) {
        int f = tid + j * 256;
        kd[j] = Kv[(size_t)(t0n + (f >> 3)) * 8 + (f & 7)];
        vd[j] = Vv[(size_t)(f >> 4) * 256 + (t0n >> 3) + (f & 15)];
      }
    }
    __syncthreads();

    // ---- S^T = K·Q^T, pipelined against EPV ----
    f32x16 sacc[4];
#pragma unroll
    for (int tt = 0; tt < 4; ++tt)
#pragma unroll
      for (int j = 0; j < 16; ++j) sacc[tt][j] = 0.f;

    __builtin_amdgcn_s_setprio(1);
#pragma unroll
    for (int ks = 0; ks < 4; ++ks)
#pragma unroll
      for (int tt = 0; tt < 2; ++tt) {
        bf16x8 a = *(const bf16x8*)&Ks[tt * 32 + l31][ks * 16 + L * 8];
        sacc[tt] = __builtin_amdgcn_mfma_f32_32x32x16_bf16(a, qfrag[ks], sacc[tt], 0, 0, 0);
      }
    __builtin_amdgcn_s_setprio(0);

    EPV(sacc[0], 0);               // overlaps S(0,1) drain

    __builtin_amdgcn_s_setprio(1);
#pragma unroll
    for (int ks = 0; ks < 4; ++ks)
#pragma unroll
      for (int tt = 2; tt < 4; ++tt) {
        bf16x8 a = *(const bf16x8*)&Ks[tt * 32 + l31][ks * 16 + L * 8];
        sacc[tt] = __builtin_amdgcn_mfma_f32_32x32x16_bf16(a, qfrag[ks], sacc[tt], 0, 0, 0);
      }
    __builtin_amdgcn_s_setprio(0);

    EPV(sacc[1], 1);               // overlaps S(2,3) drain
    EPV(sacc[2], 2);
    EPV(sacc[3], 3);
  }

  l_run += __shfl_xor(l_run, 32, 64);   // q-column's rows split between lane pair

  // ---- epilogue: O^T -> LDS -> row-major coalesced float4 stores ----
  __syncthreads();
  float* Os = (float*)smem + wave * (32 * 68);
  float inv = 1.0f / l_run;
#pragma unroll
  for (int mt = 0; mt < 2; ++mt)
#pragma unroll
    for (int rq = 0; rq < 4; ++rq) {
      f32x4 v;
      v.x = oacc[mt][4 * rq + 0] * inv;
      v.y = oacc[mt][4 * rq + 1] * inv;
      v.z = oacc[mt][4 * rq + 2] * inv;
      v.w = oacc[mt][4 * rq + 3] * inv;
      int e0 = mt * 32 + 8 * rq + 4 * L;
      *(f32x4*)&Os[l31 * 68 + e0] = v;
    }
#pragma unroll
  for (int p = 0; p < 8; ++p) {
    int q = (lane >> 4) + 4 * p;
    int e4 = lane & 15;
    float4 t = *(const float4*)&Os[q * 68 + e4 * 4];
    *(float4*)&out[((size_t)(b * S_LEN + q0 + wave * 32 + q)) * DMODEL + h * 64 + e4 * 4] = t;
  }
}

extern "C" void kernel_launch(void* const* d_in, const int* in_sizes, int n_in,
                              void* d_out, int out_size, void* d_ws, size_t ws_size,
                              hipStream_t stream) {
  const float* seq = (const float*)d_in[0];
  const float* Wq  = (const float*)d_in[1];
  const float* Wk  = (const float*)d_in[2];
  const float* Wv  = (const float*)d_in[3];
  const float* bq  = (const float*)d_in[4];
  const float* bk  = (const float*)d_in[5];
  const float* bv  = (const float*)d_in[6];
  float* out = (float*)d_out;

  const size_t wb = 3 * 49152 * sizeof(unsigned short);                // 294912 B
  const size_t qb = (size_t)NBH * S_LEN * 64 * sizeof(unsigned short); // 12.58 MB each
  unsigned short* Wb  = (unsigned short*)d_ws;
  unsigned short* Qp  = (unsigned short*)((char*)d_ws + wb);
  unsigned short* Kp  = (unsigned short*)((char*)d_ws + wb + qb);
  unsigned short* VTp = (unsigned short*)((char*)d_ws + wb + 2 * qb);

  w_cvt<<<dim3(144), 256, 0, stream>>>(Wq, Wk, Wv, Wb);
  qkv_proj<<<dim3(16 * NBH), 256, 0, stream>>>(seq, Wb, bq, bk, bv, Qp, Kp, VTp);
  flash_attn<<<dim3(16 * NBH), 256, 0, stream>>>(Qp, Kp, VTp, out);
}

// Round 2
// 221.493 us; speedup vs baseline: 1.0341x; 1.0341x over previous
//
#include <hip/hip_runtime.h>
#include <hip/hip_bf16.h>

#define S_LEN 2048
#define NHEAD 12
#define NBH 48          // B*H
#define DMODEL 768
#define BR 128          // q rows per block (4 q-waves x 32)
#define BC 128          // keys per K-tile

typedef __bf16 bf16x8 __attribute__((ext_vector_type(8)));
typedef float f32x4  __attribute__((ext_vector_type(4)));
typedef float f32x16 __attribute__((ext_vector_type(16)));

union B8U { uint4 u; bf16x8 b; };

__device__ __forceinline__ unsigned bf16rne(float f) {
  unsigned u = __float_as_uint(f);
  return (u + 0x7fffu + ((u >> 16) & 1u)) >> 16;
}

// ============ Kernel 0: weights fp32 -> bf16, once (294 KB total) ============
__global__ __launch_bounds__(256)
void w_cvt(const float* __restrict__ Wq, const float* __restrict__ Wk,
           const float* __restrict__ Wv, unsigned short* __restrict__ Wb) {
  int idx = blockIdx.x * 256 + threadIdx.x;        // 36864 float4s total
  int mat = idx / 12288;
  int off = idx - mat * 12288;
  const float* src = (mat == 0) ? Wq : (mat == 1) ? Wk : Wv;
  float4 v = ((const float4*)src)[off];
  ushort4 o;
  o.x = (unsigned short)bf16rne(v.x);
  o.y = (unsigned short)bf16rne(v.y);
  o.z = (unsigned short)bf16rne(v.z);
  o.w = (unsigned short)bf16rne(v.w);
  ((ushort4*)(Wb + (size_t)mat * 49152))[off] = o;
}

// ================= Kernel 1: per-head QKV projection (MFMA) =================
__global__ __launch_bounds__(256, 3)
void qkv_proj(const float* __restrict__ seq,
              const unsigned short* __restrict__ Wb,
              const float* __restrict__ bq, const float* __restrict__ bk,
              const float* __restrict__ bv,
              unsigned short* __restrict__ Qp, unsigned short* __restrict__ Kp,
              unsigned short* __restrict__ VTp) {
  __shared__ __align__(16) unsigned short xs[128][72];   // 18432 B, reused as Rt/Vt

  const int tid  = threadIdx.x;
  const int lane = tid & 63;
  const int wave = tid >> 6;
  const int L    = lane >> 5;
  const int l31  = lane & 31;
  const int bh    = blockIdx.x % NBH;    // XCD pin matches flash (id%8 == bh%8)
  const int stile = blockIdx.x / NBH;    // 0..15
  const int b = bh / NHEAD, h = bh % NHEAD;
  const int s0 = stile * 128;

  // ---- stage x tile [128][64] fp32 -> bf16(RNE) LDS, coalesced ----
#pragma unroll
  for (int p = 0; p < 8; ++p) {
    int f = tid + p * 256;
    int row = f >> 4, c4 = f & 15;
    float4 x = *(const float4*)&seq[((size_t)(b * S_LEN + s0 + row)) * DMODEL + h * 64 + c4 * 4];
    uint2 d;
    d.x = bf16rne(x.x) | (bf16rne(x.y) << 16);
    d.y = bf16rne(x.z) | (bf16rne(x.w) << 16);
    *(uint2*)&xs[row][c4 * 4] = d;
  }
  __syncthreads();

  // x frags: lane holds x[s=wave*32+l31][d=ks*16+L*8 ..+8]
  bf16x8 af[4];
#pragma unroll
  for (int ks = 0; ks < 4; ++ks)
    af[ks] = *(const bf16x8*)&xs[wave * 32 + l31][ks * 16 + L * 8];

  // ---- compute all 6 acc tiles (Q,K: C[e][s]; V: C[s][e]) ----
  f32x16 qacc[2], kacc[2], vacc[2];
#pragma unroll
  for (int nt = 0; nt < 2; ++nt) {
    const int e = nt * 32 + l31;
    bf16x8 wf[4];
#pragma unroll
    for (int i = 0; i < 16; ++i) { qacc[nt][i] = 0.f; kacc[nt][i] = 0.f; vacc[nt][i] = 0.f; }
#pragma unroll
    for (int ks = 0; ks < 4; ++ks)
      wf[ks] = *(const bf16x8*)&Wb[(size_t)h * 4096 + (size_t)e * 64 + ks * 16 + L * 8];
#pragma unroll
    for (int ks = 0; ks < 4; ++ks)
      qacc[nt] = __builtin_amdgcn_mfma_f32_32x32x16_bf16(wf[ks], af[ks], qacc[nt], 0, 0, 0);
#pragma unroll
    for (int ks = 0; ks < 4; ++ks)
      wf[ks] = *(const bf16x8*)&Wb[49152 + (size_t)h * 4096 + (size_t)e * 64 + ks * 16 + L * 8];
#pragma unroll
    for (int ks = 0; ks < 4; ++ks)
      kacc[nt] = __builtin_amdgcn_mfma_f32_32x32x16_bf16(wf[ks], af[ks], kacc[nt], 0, 0, 0);
#pragma unroll
    for (int ks = 0; ks < 4; ++ks)
      wf[ks] = *(const bf16x8*)&Wb[2 * 49152 + (size_t)h * 4096 + (size_t)e * 64 + ks * 16 + L * 8];
#pragma unroll
    for (int ks = 0; ks < 4; ++ks)
      vacc[nt] = __builtin_amdgcn_mfma_f32_32x32x16_bf16(af[ks], wf[ks], vacc[nt], 0, 0, 0);
  }
  __syncthreads();                       // xs (af source) dead for all waves

  const float qs = 0.18033688011112042f; // log2(e)/8 (exp2-domain softmax)

  // ---- Q then K: C[e][s] -> Rt[s][e] in LDS -> coalesced uint4 stores ----
  unsigned short (*Rt)[72] = (unsigned short(*)[72])xs;   // [128 s][72] 18432 B
#pragma unroll
  for (int mat = 0; mat < 2; ++mat) {
    const f32x16* A = (mat == 0) ? qacc : kacc;
    const float* bp0 = (mat == 0) ? bq : bk;
    float sc = (mat == 0) ? qs : 1.0f;
#pragma unroll
    for (int nt = 0; nt < 2; ++nt)
#pragma unroll
      for (int rq = 0; rq < 4; ++rq) {
        int e0 = nt * 32 + 8 * rq + 4 * L;
        const float* bp = bp0 + h * 64 + e0;
        ushort4 pv;
        pv.x = (unsigned short)bf16rne((A[nt][4 * rq + 0] + bp[0]) * sc);
        pv.y = (unsigned short)bf16rne((A[nt][4 * rq + 1] + bp[1]) * sc);
        pv.z = (unsigned short)bf16rne((A[nt][4 * rq + 2] + bp[2]) * sc);
        pv.w = (unsigned short)bf16rne((A[nt][4 * rq + 3] + bp[3]) * sc);
        *(ushort4*)&Rt[wave * 32 + l31][e0] = pv;
      }
    __syncthreads();
    unsigned short* P = (mat == 0) ? Qp : Kp;
#pragma unroll
    for (int p = 0; p < 4; ++p) {
      int f = tid + p * 256;               // 1024 x 16B chunks
      int row = f >> 3, c = f & 7;
      uint4 d = *(const uint4*)&Rt[row][c * 8];
      *(uint4*)&P[((size_t)bh * S_LEN + s0 + row) * 64 + c * 8] = d;
    }
    __syncthreads();                       // LDS reads done before reuse
  }

  // ---- V: C[s][e] -> Vt[e][s] in LDS -> coalesced uint4 stores ----
  unsigned short (*Vt)[136] = (unsigned short(*)[136])xs;  // [64 e][136] 17408 B
#pragma unroll
  for (int nt = 0; nt < 2; ++nt) {
    const int e = nt * 32 + l31;
    float bias = bv[h * 64 + e];
#pragma unroll
    for (int rq = 0; rq < 4; ++rq) {
      ushort4 pv;
      pv.x = (unsigned short)bf16rne(vacc[nt][4 * rq + 0] + bias);
      pv.y = (unsigned short)bf16rne(vacc[nt][4 * rq + 1] + bias);
      pv.z = (unsigned short)bf16rne(vacc[nt][4 * rq + 2] + bias);
      pv.w = (unsigned short)bf16rne(vacc[nt][4 * rq + 3] + bias);
      *(ushort4*)&Vt[e][wave * 32 + 8 * rq + 4 * L] = pv;
    }
  }
  __syncthreads();
#pragma unroll
  for (int p = 0; p < 4; ++p) {
    int f = tid + p * 256;                 // 1024 x 16B chunks
    int row = f >> 4, c = f & 15;
    uint4 d = *(const uint4*)&Vt[row][c * 8];
    *(uint4*)&VTp[((size_t)bh * 64 + row) * S_LEN + s0 + c * 8] = d;
  }
}

// ============ Kernel 2: flash attention, fixed-base softmax ============
// R6 structural changes:
//  - 8 waves/block (512 thr): qw=wave&3 owns 32 q-rows, kh=wave>>2 owns half
//    of each 128-key tile. Fixed-base softmax is a PURE SUM -> key-split
//    partials (O^T, l) merge with one add through LDS at the end. Same LDS
//    staging traffic, same MFMA total, 2x resident waves/CU for latency hiding.
//  - prefetch moved AFTER the 2nd barrier: hipcc drains vmcnt(0) before every
//    s_barrier, so the old placement forced the just-issued K/V loads to
//    COMPLETE before compute. Now the whole compute phase covers them.
//  - phase stagger removed (R1: FETCH_SIZE doubled, zero time effect).
__global__ __launch_bounds__(512)
void flash_attn(const unsigned short* __restrict__ Qp,
                const unsigned short* __restrict__ Kp,
                const unsigned short* __restrict__ VTp,
                float* __restrict__ out) {
  __shared__ __align__(16) char smem[35840];
  unsigned short (*Ks)[72]  = (unsigned short(*)[72])smem;            // [128][72]
  unsigned short (*Vs)[136] = (unsigned short(*)[136])(smem + 18432); // [64][136]

  const int tid  = threadIdx.x;
  const int wave = tid >> 6;
  const int lane = tid & 63;
  const int L    = lane >> 5;
  const int l31  = lane & 31;
  const int qw   = wave & 3;    // q-row group
  const int kh   = wave >> 2;   // key half of each tile
  // XCD pinning: id%8 == bh%8 -> all 16 q-tiles of a bh share one XCD's L2
  const int bh = blockIdx.x % NBH;
  const int qx = blockIdx.x / NBH;
  const int b = bh / NHEAD, h = bh % NHEAD;
  const int q0 = qx * BR;

  // Q frags (B-operand): lane holds Q[q=l31][d=ks*16+L*8+j]
  bf16x8 qfrag[4];
  {
    const uint4* Qv = (const uint4*)Qp;
#pragma unroll
    for (int ks = 0; ks < 4; ++ks) {
      B8U t;
      t.u = Qv[((size_t)bh * S_LEN + q0 + qw * 32 + l31) * 8 + ks * 2 + L];
      qfrag[ks] = t.b;
    }
  }

  f32x16 oacc[2];
#pragma unroll
  for (int mt = 0; mt < 2; ++mt)
#pragma unroll
    for (int i = 0; i < 16; ++i) oacc[mt][i] = 0.f;
  float l_run = 0.f;

  const uint4* Kv = (const uint4*)Kp  + (size_t)bh * S_LEN * 8;
  const uint4* Vv = (const uint4*)VTp + (size_t)bh * 64 * 256;

  uint4 kd[2], vd[2];
#pragma unroll
  for (int j = 0; j < 2; ++j) {
    int f = tid + j * 512;
    kd[j] = Kv[(size_t)(f >> 3) * 8 + (f & 7)];
    vd[j] = Vv[(size_t)(f >> 4) * 256 + (f & 15)];
  }

  // EPV: exp2 + bf16-truncate pack + PV-MFMA for one 32-key score tile (tt is
  // the GLOBAL 32-key slot 0..3). l sums the SAME truncated values so rounding
  // bias cancels in p/l.
  auto EPV = [&](const f32x16& sc, int tt) {
    unsigned pk[8];
    float la = 0.f, lb = 0.f;
#pragma unroll
    for (int p = 0; p < 8; ++p) {
      unsigned u0 = __float_as_uint(__builtin_amdgcn_exp2f(sc[2 * p]));
      unsigned u1 = __float_as_uint(__builtin_amdgcn_exp2f(sc[2 * p + 1]));
      unsigned d = __builtin_amdgcn_perm(u1, u0, 0x07060302);  // {hi16(u1),hi16(u0)}
      pk[p] = d;
      la += __uint_as_float(d << 16);
      lb += __uint_as_float(d & 0xffff0000u);
    }
    l_run += la + lb;
#pragma unroll
    for (int mk = 0; mk < 2; ++mk) {
      const int m = 2 * tt + mk;
      unsigned a0 = pk[4 * mk + 0], a1 = pk[4 * mk + 1];
      unsigned b0 = pk[4 * mk + 2], b1 = pk[4 * mk + 3];
      asm("v_permlane32_swap_b32 %0, %1" : "+v"(a0), "+v"(b0));
      asm("v_permlane32_swap_b32 %0, %1" : "+v"(a1), "+v"(b1));
      B8U t;
      t.u.x = a0; t.u.y = a1; t.u.z = b0; t.u.w = b1;
      __builtin_amdgcn_s_setprio(1);
#pragma unroll
      for (int mt = 0; mt < 2; ++mt) {
        bf16x8 va = *(const bf16x8*)&Vs[mt * 32 + l31][m * 16 + L * 8];
        oacc[mt] = __builtin_amdgcn_mfma_f32_32x32x16_bf16(va, t.b, oacc[mt], 0, 0, 0);
      }
      __builtin_amdgcn_s_setprio(0);
    }
  };

  for (int i = 0; i < S_LEN / BC; ++i) {
    __syncthreads();                 // prefetch had the whole prev compute phase
#pragma unroll
    for (int j = 0; j < 2; ++j) {
      int f = tid + j * 512;
      *(uint4*)&Ks[f >> 3][(f & 7) * 8]  = kd[j];
      *(uint4*)&Vs[f >> 4][(f & 15) * 8] = vd[j];
    }
    __syncthreads();
    if (i + 1 < S_LEN / BC) {        // issue prefetch AFTER the barrier drain
      int t0n = (i + 1) * BC;
#pragma unroll
      for (int j = 0; j < 2; ++j) {
        int f = tid + j * 512;
        kd[j] = Kv[(size_t)(t0n + (f >> 3)) * 8 + (f & 7)];
        vd[j] = Vv[(size_t)(f >> 4) * 256 + (t0n >> 3) + (f & 15)];
      }
    }

    // ---- S^T = K·Q^T for this wave's key half (tiles kh*2, kh*2+1) ----
    f32x16 sacc[2];
#pragma unroll
    for (int tl = 0; tl < 2; ++tl)
#pragma unroll
      for (int j = 0; j < 16; ++j) sacc[tl][j] = 0.f;

    __builtin_amdgcn_s_setprio(1);
#pragma unroll
    for (int ks = 0; ks < 4; ++ks)
#pragma unroll
      for (int tl = 0; tl < 2; ++tl) {
        bf16x8 a = *(const bf16x8*)&Ks[(kh * 2 + tl) * 32 + l31][ks * 16 + L * 8];
        sacc[tl] = __builtin_amdgcn_mfma_f32_32x32x16_bf16(a, qfrag[ks], sacc[tl], 0, 0, 0);
      }
    __builtin_amdgcn_s_setprio(0);

    EPV(sacc[0], kh * 2 + 0);
    EPV(sacc[1], kh * 2 + 1);
  }

  l_run += __shfl_xor(l_run, 32, 64);   // q-column's rows split between lane pair

  // ---- merge the two key-half partials (pure sums), then normalize ----
  __syncthreads();                       // Ks/Vs dead for all waves
  float* M  = (float*)smem;              // [4 qw][32 q][68 e]  34816 B
  float* Ml = (float*)(smem + 34816);    // [4 qw][32 q] l      512 B
  if (kh == 1) {
    float* Mw = M + qw * (32 * 68);
#pragma unroll
    for (int mt = 0; mt < 2; ++mt)
#pragma unroll
      for (int rq = 0; rq < 4; ++rq) {
        f32x4 v;
        v.x = oacc[mt][4 * rq + 0];
        v.y = oacc[mt][4 * rq + 1];
        v.z = oacc[mt][4 * rq + 2];
        v.w = oacc[mt][4 * rq + 3];
        int e0 = mt * 32 + 8 * rq + 4 * L;
        *(f32x4*)&Mw[l31 * 68 + e0] = v;
      }
    if (lane < 32) Ml[qw * 32 + l31] = l_run;
  }
  __syncthreads();
  if (kh == 0) {
    float* Mw = M + qw * (32 * 68);
#pragma unroll
    for (int mt = 0; mt < 2; ++mt)
#pragma unroll
      for (int rq = 0; rq < 4; ++rq) {
        int e0 = mt * 32 + 8 * rq + 4 * L;
        f32x4 v = *(const f32x4*)&Mw[l31 * 68 + e0];
        oacc[mt][4 * rq + 0] += v.x;
        oacc[mt][4 * rq + 1] += v.y;
        oacc[mt][4 * rq + 2] += v.z;
        oacc[mt][4 * rq + 3] += v.w;
      }
    l_run += Ml[qw * 32 + l31];
  }
  __syncthreads();                       // M dead before Os reuse

  if (kh == 0) {
    float* Os = (float*)smem + qw * (32 * 68);
    float inv = 1.0f / l_run;
#pragma unroll
    for (int mt = 0; mt < 2; ++mt)
#pragma unroll
      for (int rq = 0; rq < 4; ++rq) {
        f32x4 v;
        v.x = oacc[mt][4 * rq + 0] * inv;
        v.y = oacc[mt][4 * rq + 1] * inv;
        v.z = oacc[mt][4 * rq + 2] * inv;
        v.w = oacc[mt][4 * rq + 3] * inv;
        int e0 = mt * 32 + 8 * rq + 4 * L;
        *(f32x4*)&Os[l31 * 68 + e0] = v;
      }
#pragma unroll
    for (int p = 0; p < 8; ++p) {
      int q = (lane >> 4) + 4 * p;
      int e4 = lane & 15;
      float4 t = *(const float4*)&Os[q * 68 + e4 * 4];
      *(float4*)&out[((size_t)(b * S_LEN + q0 + qw * 32 + q)) * DMODEL + h * 64 + e4 * 4] = t;
    }
  }
}

extern "C" void kernel_launch(void* const* d_in, const int* in_sizes, int n_in,
                              void* d_out, int out_size, void* d_ws, size_t ws_size,
                              hipStream_t stream) {
  const float* seq = (const float*)d_in[0];
  const float* Wq  = (const float*)d_in[1];
  const float* Wk  = (const float*)d_in[2];
  const float* Wv  = (const float*)d_in[3];
  const float* bq  = (const float*)d_in[4];
  const float* bk  = (const float*)d_in[5];
  const float* bv  = (const float*)d_in[6];
  float* out = (float*)d_out;

  const size_t wb = 3 * 49152 * sizeof(unsigned short);                // 294912 B
  const size_t qb = (size_t)NBH * S_LEN * 64 * sizeof(unsigned short); // 12.58 MB each
  unsigned short* Wb  = (unsigned short*)d_ws;
  unsigned short* Qp  = (unsigned short*)((char*)d_ws + wb);
  unsigned short* Kp  = (unsigned short*)((char*)d_ws + wb + qb);
  unsigned short* VTp = (unsigned short*)((char*)d_ws + wb + 2 * qb);

  w_cvt<<<dim3(144), 256, 0, stream>>>(Wq, Wk, Wv, Wb);
  qkv_proj<<<dim3(16 * NBH), 256, 0, stream>>>(seq, Wb, bq, bk, bv, Qp, Kp, VTp);
  flash_attn<<<dim3(16 * NBH), 512, 0, stream>>>(Qp, Kp, VTp, out);
}

// Round 3
// 163.154 us; speedup vs baseline: 1.4038x; 1.3576x over previous
//
#include <hip/hip_runtime.h>
#include <hip/hip_bf16.h>

#define S_LEN 2048
#define NHEAD 12
#define NBH 48          // B*H
#define DMODEL 768
#define BR 128          // q rows per block (4 q-waves x 32)
#define BC 128          // keys per K-tile

typedef __bf16 bf16x8 __attribute__((ext_vector_type(8)));
typedef float f32x4  __attribute__((ext_vector_type(4)));
typedef float f32x16 __attribute__((ext_vector_type(16)));

union B8U { uint4 u; bf16x8 b; };

__device__ __forceinline__ unsigned bf16rne(float f) {
  unsigned u = __float_as_uint(f);
  return (u + 0x7fffu + ((u >> 16) & 1u)) >> 16;
}

// ============ Kernel 0: weights fp32 -> bf16, once (294 KB total) ============
__global__ __launch_bounds__(256)
void w_cvt(const float* __restrict__ Wq, const float* __restrict__ Wk,
           const float* __restrict__ Wv, unsigned short* __restrict__ Wb) {
  int idx = blockIdx.x * 256 + threadIdx.x;        // 36864 float4s total
  int mat = idx / 12288;
  int off = idx - mat * 12288;
  const float* src = (mat == 0) ? Wq : (mat == 1) ? Wk : Wv;
  float4 v = ((const float4*)src)[off];
  ushort4 o;
  o.x = (unsigned short)bf16rne(v.x);
  o.y = (unsigned short)bf16rne(v.y);
  o.z = (unsigned short)bf16rne(v.z);
  o.w = (unsigned short)bf16rne(v.w);
  ((ushort4*)(Wb + (size_t)mat * 49152))[off] = o;
}

// ================= Kernel 1: per-head QKV projection (MFMA) =================
__global__ __launch_bounds__(256, 3)
void qkv_proj(const float* __restrict__ seq,
              const unsigned short* __restrict__ Wb,
              const float* __restrict__ bq, const float* __restrict__ bk,
              const float* __restrict__ bv,
              unsigned short* __restrict__ Qp, unsigned short* __restrict__ Kp,
              unsigned short* __restrict__ VTp) {
  __shared__ __align__(16) unsigned short xs[128][72];   // 18432 B, reused as Rt/Vt

  const int tid  = threadIdx.x;
  const int lane = tid & 63;
  const int wave = tid >> 6;
  const int L    = lane >> 5;
  const int l31  = lane & 31;
  const int bh    = blockIdx.x % NBH;    // XCD pin matches flash (id%8 == bh%8)
  const int stile = blockIdx.x / NBH;    // 0..15
  const int b = bh / NHEAD, h = bh % NHEAD;
  const int s0 = stile * 128;

  // ---- stage x tile [128][64] fp32 -> bf16(RNE) LDS, coalesced ----
#pragma unroll
  for (int p = 0; p < 8; ++p) {
    int f = tid + p * 256;
    int row = f >> 4, c4 = f & 15;
    float4 x = *(const float4*)&seq[((size_t)(b * S_LEN + s0 + row)) * DMODEL + h * 64 + c4 * 4];
    uint2 d;
    d.x = bf16rne(x.x) | (bf16rne(x.y) << 16);
    d.y = bf16rne(x.z) | (bf16rne(x.w) << 16);
    *(uint2*)&xs[row][c4 * 4] = d;
  }
  __syncthreads();

  // x frags: lane holds x[s=wave*32+l31][d=ks*16+L*8 ..+8]
  bf16x8 af[4];
#pragma unroll
  for (int ks = 0; ks < 4; ++ks)
    af[ks] = *(const bf16x8*)&xs[wave * 32 + l31][ks * 16 + L * 8];

  // ---- compute all 6 acc tiles (Q,K: C[e][s]; V: C[s][e]) ----
  f32x16 qacc[2], kacc[2], vacc[2];
#pragma unroll
  for (int nt = 0; nt < 2; ++nt) {
    const int e = nt * 32 + l31;
    bf16x8 wf[4];
#pragma unroll
    for (int i = 0; i < 16; ++i) { qacc[nt][i] = 0.f; kacc[nt][i] = 0.f; vacc[nt][i] = 0.f; }
#pragma unroll
    for (int ks = 0; ks < 4; ++ks)
      wf[ks] = *(const bf16x8*)&Wb[(size_t)h * 4096 + (size_t)e * 64 + ks * 16 + L * 8];
#pragma unroll
    for (int ks = 0; ks < 4; ++ks)
      qacc[nt] = __builtin_amdgcn_mfma_f32_32x32x16_bf16(wf[ks], af[ks], qacc[nt], 0, 0, 0);
#pragma unroll
    for (int ks = 0; ks < 4; ++ks)
      wf[ks] = *(const bf16x8*)&Wb[49152 + (size_t)h * 4096 + (size_t)e * 64 + ks * 16 + L * 8];
#pragma unroll
    for (int ks = 0; ks < 4; ++ks)
      kacc[nt] = __builtin_amdgcn_mfma_f32_32x32x16_bf16(wf[ks], af[ks], kacc[nt], 0, 0, 0);
#pragma unroll
    for (int ks = 0; ks < 4; ++ks)
      wf[ks] = *(const bf16x8*)&Wb[2 * 49152 + (size_t)h * 4096 + (size_t)e * 64 + ks * 16 + L * 8];
#pragma unroll
    for (int ks = 0; ks < 4; ++ks)
      vacc[nt] = __builtin_amdgcn_mfma_f32_32x32x16_bf16(af[ks], wf[ks], vacc[nt], 0, 0, 0);
  }
  __syncthreads();                       // xs (af source) dead for all waves

  const float qs = 0.18033688011112042f; // log2(e)/8 (exp2-domain softmax)

  // ---- Q then K: C[e][s] -> Rt[s][e] in LDS -> coalesced uint4 stores ----
  unsigned short (*Rt)[72] = (unsigned short(*)[72])xs;   // [128 s][72] 18432 B
#pragma unroll
  for (int mat = 0; mat < 2; ++mat) {
    const f32x16* A = (mat == 0) ? qacc : kacc;
    const float* bp0 = (mat == 0) ? bq : bk;
    float sc = (mat == 0) ? qs : 1.0f;
#pragma unroll
    for (int nt = 0; nt < 2; ++nt)
#pragma unroll
      for (int rq = 0; rq < 4; ++rq) {
        int e0 = nt * 32 + 8 * rq + 4 * L;
        const float* bp = bp0 + h * 64 + e0;
        ushort4 pv;
        pv.x = (unsigned short)bf16rne((A[nt][4 * rq + 0] + bp[0]) * sc);
        pv.y = (unsigned short)bf16rne((A[nt][4 * rq + 1] + bp[1]) * sc);
        pv.z = (unsigned short)bf16rne((A[nt][4 * rq + 2] + bp[2]) * sc);
        pv.w = (unsigned short)bf16rne((A[nt][4 * rq + 3] + bp[3]) * sc);
        *(ushort4*)&Rt[wave * 32 + l31][e0] = pv;
      }
    __syncthreads();
    unsigned short* P = (mat == 0) ? Qp : Kp;
#pragma unroll
    for (int p = 0; p < 4; ++p) {
      int f = tid + p * 256;               // 1024 x 16B chunks
      int row = f >> 3, c = f & 7;
      uint4 d = *(const uint4*)&Rt[row][c * 8];
      *(uint4*)&P[((size_t)bh * S_LEN + s0 + row) * 64 + c * 8] = d;
    }
    __syncthreads();                       // LDS reads done before reuse
  }

  // ---- V: C[s][e] -> Vt[e][s] in LDS -> coalesced uint4 stores ----
  unsigned short (*Vt)[136] = (unsigned short(*)[136])xs;  // [64 e][136] 17408 B
#pragma unroll
  for (int nt = 0; nt < 2; ++nt) {
    const int e = nt * 32 + l31;
    float bias = bv[h * 64 + e];
#pragma unroll
    for (int rq = 0; rq < 4; ++rq) {
      ushort4 pv;
      pv.x = (unsigned short)bf16rne(vacc[nt][4 * rq + 0] + bias);
      pv.y = (unsigned short)bf16rne(vacc[nt][4 * rq + 1] + bias);
      pv.z = (unsigned short)bf16rne(vacc[nt][4 * rq + 2] + bias);
      pv.w = (unsigned short)bf16rne(vacc[nt][4 * rq + 3] + bias);
      *(ushort4*)&Vt[e][wave * 32 + 8 * rq + 4 * L] = pv;
    }
  }
  __syncthreads();
#pragma unroll
  for (int p = 0; p < 4; ++p) {
    int f = tid + p * 256;                 // 1024 x 16B chunks
    int row = f >> 4, c = f & 15;
    uint4 d = *(const uint4*)&Vt[row][c * 8];
    *(uint4*)&VTp[((size_t)bh * 64 + row) * S_LEN + s0 + c * 8] = d;
  }
}

// ============ Kernel 2: flash attention, fixed-base softmax ============
// R7 structural change: double-buffered K/V LDS + ONE barrier per iter with
// ZERO outstanding vmem at the barrier. The old single-buffer loop convoyed
// all waves on 2 drained barriers per K-tile (R2: MfmaUtil 15% with every
// pipe <30% busy -> structural wait, not capacity). New schedule per iter:
//   load(i+1)->regs  (top; whole compute phase of latency cover)
//   compute S+EPV from buf[cur]
//   ds_write regs -> buf[cur^1]   (vmcnt drained HERE, under cover)
//   __syncthreads()               (free drain: nothing outstanding)
// Double buffer makes write(i+1) vs read(i) conflict-free -> 2nd barrier gone.
// LDS 71680 B -> 2 blocks/CU (occupancy proved not the lever in R2).
__global__ __launch_bounds__(512)
void flash_attn(const unsigned short* __restrict__ Qp,
                const unsigned short* __restrict__ Kp,
                const unsigned short* __restrict__ VTp,
                float* __restrict__ out) {
  __shared__ __align__(16) char smem[71680];
  unsigned short (*Ks)[128][72]  = (unsigned short(*)[128][72])smem;            // 2x18432 B
  unsigned short (*Vs)[64][136]  = (unsigned short(*)[64][136])(smem + 36864);  // 2x17408 B

  const int tid  = threadIdx.x;
  const int wave = tid >> 6;
  const int lane = tid & 63;
  const int L    = lane >> 5;
  const int l31  = lane & 31;
  const int qw   = wave & 3;    // q-row group
  const int kh   = wave >> 2;   // key half of each tile
  // XCD pinning: id%8 == bh%8 -> all 16 q-tiles of a bh share one XCD's L2
  const int bh = blockIdx.x % NBH;
  const int qx = blockIdx.x / NBH;
  const int b = bh / NHEAD, h = bh % NHEAD;
  const int q0 = qx * BR;

  // Q frags (B-operand): lane holds Q[q=l31][d=ks*16+L*8+j]
  bf16x8 qfrag[4];
  {
    const uint4* Qv = (const uint4*)Qp;
#pragma unroll
    for (int ks = 0; ks < 4; ++ks) {
      B8U t;
      t.u = Qv[((size_t)bh * S_LEN + q0 + qw * 32 + l31) * 8 + ks * 2 + L];
      qfrag[ks] = t.b;
    }
  }

  f32x16 oacc[2];
#pragma unroll
  for (int mt = 0; mt < 2; ++mt)
#pragma unroll
    for (int i = 0; i < 16; ++i) oacc[mt][i] = 0.f;
  float l_run = 0.f;

  const uint4* Kv = (const uint4*)Kp  + (size_t)bh * S_LEN * 8;
  const uint4* Vv = (const uint4*)VTp + (size_t)bh * 64 * 256;

  uint4 kd[2], vd[2];
#pragma unroll
  for (int j = 0; j < 2; ++j) {
    int f = tid + j * 512;
    kd[j] = Kv[(size_t)(f >> 3) * 8 + (f & 7)];
    vd[j] = Vv[(size_t)(f >> 4) * 256 + (f & 15)];
  }

  // EPV: exp2 + bf16-truncate pack + PV-MFMA for one 32-key score tile (tt is
  // the GLOBAL 32-key slot 0..3). l sums the SAME truncated values so rounding
  // bias cancels in p/l.
  int cur = 0;
  auto EPV = [&](const f32x16& sc, int tt) {
    unsigned pk[8];
    float la = 0.f, lb = 0.f;
#pragma unroll
    for (int p = 0; p < 8; ++p) {
      unsigned u0 = __float_as_uint(__builtin_amdgcn_exp2f(sc[2 * p]));
      unsigned u1 = __float_as_uint(__builtin_amdgcn_exp2f(sc[2 * p + 1]));
      unsigned d = __builtin_amdgcn_perm(u1, u0, 0x07060302);  // {hi16(u1),hi16(u0)}
      pk[p] = d;
      la += __uint_as_float(d << 16);
      lb += __uint_as_float(d & 0xffff0000u);
    }
    l_run += la + lb;
#pragma unroll
    for (int mk = 0; mk < 2; ++mk) {
      const int m = 2 * tt + mk;
      unsigned a0 = pk[4 * mk + 0], a1 = pk[4 * mk + 1];
      unsigned b0 = pk[4 * mk + 2], b1 = pk[4 * mk + 3];
      asm("v_permlane32_swap_b32 %0, %1" : "+v"(a0), "+v"(b0));
      asm("v_permlane32_swap_b32 %0, %1" : "+v"(a1), "+v"(b1));
      B8U t;
      t.u.x = a0; t.u.y = a1; t.u.z = b0; t.u.w = b1;
      __builtin_amdgcn_s_setprio(1);
#pragma unroll
      for (int mt = 0; mt < 2; ++mt) {
        bf16x8 va = *(const bf16x8*)&Vs[cur][mt * 32 + l31][m * 16 + L * 8];
        oacc[mt] = __builtin_amdgcn_mfma_f32_32x32x16_bf16(va, t.b, oacc[mt], 0, 0, 0);
      }
      __builtin_amdgcn_s_setprio(0);
    }
  };

  // prologue: stage tile 0 into buf 0
#pragma unroll
  for (int j = 0; j < 2; ++j) {
    int f = tid + j * 512;
    *(uint4*)&Ks[0][f >> 3][(f & 7) * 8]  = kd[j];
    *(uint4*)&Vs[0][f >> 4][(f & 15) * 8] = vd[j];
  }
  __syncthreads();

  for (int i = 0; i < S_LEN / BC; ++i) {
    if (i + 1 < S_LEN / BC) {        // issue next-tile loads; compute covers them
      int t0n = (i + 1) * BC;
#pragma unroll
      for (int j = 0; j < 2; ++j) {
        int f = tid + j * 512;
        kd[j] = Kv[(size_t)(t0n + (f >> 3)) * 8 + (f & 7)];
        vd[j] = Vv[(size_t)(f >> 4) * 256 + (t0n >> 3) + (f & 15)];
      }
    }

    // ---- S^T = K·Q^T for this wave's key half (tiles kh*2, kh*2+1) ----
    f32x16 sacc[2];
#pragma unroll
    for (int tl = 0; tl < 2; ++tl)
#pragma unroll
      for (int j = 0; j < 16; ++j) sacc[tl][j] = 0.f;

    __builtin_amdgcn_s_setprio(1);
#pragma unroll
    for (int ks = 0; ks < 4; ++ks)
#pragma unroll
      for (int tl = 0; tl < 2; ++tl) {
        bf16x8 a = *(const bf16x8*)&Ks[cur][(kh * 2 + tl) * 32 + l31][ks * 16 + L * 8];
        sacc[tl] = __builtin_amdgcn_mfma_f32_32x32x16_bf16(a, qfrag[ks], sacc[tl], 0, 0, 0);
      }
    __builtin_amdgcn_s_setprio(0);

    EPV(sacc[0], kh * 2 + 0);
    EPV(sacc[1], kh * 2 + 1);

    if (i + 1 < S_LEN / BC) {        // stage next tile into the other buffer
#pragma unroll
      for (int j = 0; j < 2; ++j) {
        int f = tid + j * 512;
        *(uint4*)&Ks[cur ^ 1][f >> 3][(f & 7) * 8]  = kd[j];
        *(uint4*)&Vs[cur ^ 1][f >> 4][(f & 15) * 8] = vd[j];
      }
    }
    __syncthreads();                 // single barrier; nothing outstanding
    cur ^= 1;
  }

  l_run += __shfl_xor(l_run, 32, 64);   // q-column's rows split between lane pair

  // ---- merge the two key-half partials (pure sums), then normalize ----
  float* M  = (float*)smem;              // [4 qw][32 q][68 e]  34816 B
  float* Ml = (float*)(smem + 34816);    // [4 qw][32 q] l      512 B
  if (kh == 1) {
    float* Mw = M + qw * (32 * 68);
#pragma unroll
    for (int mt = 0; mt < 2; ++mt)
#pragma unroll
      for (int rq = 0; rq < 4; ++rq) {
        f32x4 v;
        v.x = oacc[mt][4 * rq + 0];
        v.y = oacc[mt][4 * rq + 1];
        v.z = oacc[mt][4 * rq + 2];
        v.w = oacc[mt][4 * rq + 3];
        int e0 = mt * 32 + 8 * rq + 4 * L;
        *(f32x4*)&Mw[l31 * 68 + e0] = v;
      }
    if (lane < 32) Ml[qw * 32 + l31] = l_run;
  }
  __syncthreads();
  if (kh == 0) {
    float* Mw = M + qw * (32 * 68);
#pragma unroll
    for (int mt = 0; mt < 2; ++mt)
#pragma unroll
      for (int rq = 0; rq < 4; ++rq) {
        int e0 = mt * 32 + 8 * rq + 4 * L;
        f32x4 v = *(const f32x4*)&Mw[l31 * 68 + e0];
        oacc[mt][4 * rq + 0] += v.x;
        oacc[mt][4 * rq + 1] += v.y;
        oacc[mt][4 * rq + 2] += v.z;
        oacc[mt][4 * rq + 3] += v.w;
      }
    l_run += Ml[qw * 32 + l31];
  }
  __syncthreads();                       // M dead before Os reuse

  if (kh == 0) {
    float* Os = (float*)smem + qw * (32 * 68);
    float inv = 1.0f / l_run;
#pragma unroll
    for (int mt = 0; mt < 2; ++mt)
#pragma unroll
      for (int rq = 0; rq < 4; ++rq) {
        f32x4 v;
        v.x = oacc[mt][4 * rq + 0] * inv;
        v.y = oacc[mt][4 * rq + 1] * inv;
        v.z = oacc[mt][4 * rq + 2] * inv;
        v.w = oacc[mt][4 * rq + 3] * inv;
        int e0 = mt * 32 + 8 * rq + 4 * L;
        *(f32x4*)&Os[l31 * 68 + e0] = v;
      }
#pragma unroll
    for (int p = 0; p < 8; ++p) {
      int q = (lane >> 4) + 4 * p;
      int e4 = lane & 15;
      float4 t = *(const float4*)&Os[q * 68 + e4 * 4];
      *(float4*)&out[((size_t)(b * S_LEN + q0 + qw * 32 + q)) * DMODEL + h * 64 + e4 * 4] = t;
    }
  }
}

extern "C" void kernel_launch(void* const* d_in, const int* in_sizes, int n_in,
                              void* d_out, int out_size, void* d_ws, size_t ws_size,
                              hipStream_t stream) {
  const float* seq = (const float*)d_in[0];
  const float* Wq  = (const float*)d_in[1];
  const float* Wk  = (const float*)d_in[2];
  const float* Wv  = (const float*)d_in[3];
  const float* bq  = (const float*)d_in[4];
  const float* bk  = (const float*)d_in[5];
  const float* bv  = (const float*)d_in[6];
  float* out = (float*)d_out;

  const size_t wb = 3 * 49152 * sizeof(unsigned short);                // 294912 B
  const size_t qb = (size_t)NBH * S_LEN * 64 * sizeof(unsigned short); // 12.58 MB each
  unsigned short* Wb  = (unsigned short*)d_ws;
  unsigned short* Qp  = (unsigned short*)((char*)d_ws + wb);
  unsigned short* Kp  = (unsigned short*)((char*)d_ws + wb + qb);
  unsigned short* VTp = (unsigned short*)((char*)d_ws + wb + 2 * qb);

  w_cvt<<<dim3(144), 256, 0, stream>>>(Wq, Wk, Wv, Wb);
  qkv_proj<<<dim3(16 * NBH), 256, 0, stream>>>(seq, Wb, bq, bk, bv, Qp, Kp, VTp);
  flash_attn<<<dim3(16 * NBH), 512, 0, stream>>>(Qp, Kp, VTp, out);
}

// Round 4
// 159.329 us; speedup vs baseline: 1.4375x; 1.0240x over previous
//
#include <hip/hip_runtime.h>
#include <hip/hip_bf16.h>

#define S_LEN 2048
#define NHEAD 12
#define NBH 48          // B*H
#define DMODEL 768
#define BR 128          // q rows per block (4 q-waves x 32)
#define BC 128          // keys per K-tile

typedef __bf16 bf16x8 __attribute__((ext_vector_type(8)));
typedef float f32x4  __attribute__((ext_vector_type(4)));
typedef float f32x16 __attribute__((ext_vector_type(16)));

union B8U { uint4 u; bf16x8 b; };

__device__ __forceinline__ unsigned bf16rne(float f) {
  unsigned u = __float_as_uint(f);
  return (u + 0x7fffu + ((u >> 16) & 1u)) >> 16;
}

// ============ Kernel 0: weights fp32 -> bf16, once (294 KB total) ============
__global__ __launch_bounds__(256)
void w_cvt(const float* __restrict__ Wq, const float* __restrict__ Wk,
           const float* __restrict__ Wv, unsigned short* __restrict__ Wb) {
  int idx = blockIdx.x * 256 + threadIdx.x;        // 36864 float4s total
  int mat = idx / 12288;
  int off = idx - mat * 12288;
  const float* src = (mat == 0) ? Wq : (mat == 1) ? Wk : Wv;
  float4 v = ((const float4*)src)[off];
  ushort4 o;
  o.x = (unsigned short)bf16rne(v.x);
  o.y = (unsigned short)bf16rne(v.y);
  o.z = (unsigned short)bf16rne(v.z);
  o.w = (unsigned short)bf16rne(v.w);
  ((ushort4*)(Wb + (size_t)mat * 49152))[off] = o;
}

// ================= Kernel 1: per-head QKV projection (MFMA) =================
// R8: BARRIER-FREE after the x-stage. qkv had flash's pre-R7 disease: 8 fully
// drained __syncthreads per block, 3 phase-locked blocks/CU (~75 us for a
// ~10 us memory-roofline job). Only the x-stage is cross-wave; wave w reads
// af exclusively from xs rows [32w,32w+32), so that 4608 B slice becomes the
// wave's PRIVATE transpose buffer (Rt [32][72] for Q/K, Vt [64][36] for V).
// Within-wave LDS ordering is wave-synchronous (compiler waitcnts, no
// barrier) -> 1 barrier total, waves free-run, TLP hides all latency.
__global__ __launch_bounds__(256)
void qkv_proj(const float* __restrict__ seq,
              const unsigned short* __restrict__ Wb,
              const float* __restrict__ bq, const float* __restrict__ bk,
              const float* __restrict__ bv,
              unsigned short* __restrict__ Qp, unsigned short* __restrict__ Kp,
              unsigned short* __restrict__ VTp) {
  __shared__ __align__(16) unsigned short xs[128][72];   // 18432 B

  const int tid  = threadIdx.x;
  const int lane = tid & 63;
  const int wave = tid >> 6;
  const int L    = lane >> 5;
  const int l31  = lane & 31;
  const int bh    = blockIdx.x % NBH;    // XCD pin matches flash (id%8 == bh%8)
  const int stile = blockIdx.x / NBH;    // 0..15
  const int b = bh / NHEAD, h = bh % NHEAD;
  const int s0 = stile * 128;

  // ---- stage x tile [128][64] fp32 -> bf16(RNE) LDS, coalesced ----
#pragma unroll
  for (int p = 0; p < 8; ++p) {
    int f = tid + p * 256;
    int row = f >> 4, c4 = f & 15;
    float4 x = *(const float4*)&seq[((size_t)(b * S_LEN + s0 + row)) * DMODEL + h * 64 + c4 * 4];
    uint2 d;
    d.x = bf16rne(x.x) | (bf16rne(x.y) << 16);
    d.y = bf16rne(x.z) | (bf16rne(x.w) << 16);
    *(uint2*)&xs[row][c4 * 4] = d;
  }
  __syncthreads();                       // the ONLY barrier

  // x frags: lane holds x[s=wave*32+l31][d=ks*16+L*8 ..+8]
  bf16x8 af[4];
#pragma unroll
  for (int ks = 0; ks < 4; ++ks)
    af[ks] = *(const bf16x8*)&xs[wave * 32 + l31][ks * 16 + L * 8];

  // per-wave private slice of xs (rows [32*wave, 32*wave+32) = 4608 B):
  // only THIS wave read af from these rows, so reuse needs no barrier.
  unsigned short (*Rt)[72] = (unsigned short(*)[72])(&xs[wave * 32][0]); // [32][72]
  unsigned short (*Vt)[36] = (unsigned short(*)[36])(&xs[wave * 32][0]); // [64][36]

  const float qs = 0.18033688011112042f; // log2(e)/8 (exp2-domain softmax)

  // ---- Q then K: acc C[e][s] -> bias/scale -> Rt[s][e] -> coalesced stores --
#pragma unroll
  for (int mat = 0; mat < 2; ++mat) {
    const float* bp0 = (mat == 0) ? bq : bk;
    const float sc = (mat == 0) ? qs : 1.0f;
    const size_t wofs = (size_t)mat * 49152 + (size_t)h * 4096;
    f32x16 acc[2];
#pragma unroll
    for (int nt = 0; nt < 2; ++nt) {
      const int e = nt * 32 + l31;
      bf16x8 wf[4];
#pragma unroll
      for (int i = 0; i < 16; ++i) acc[nt][i] = 0.f;
#pragma unroll
      for (int ks = 0; ks < 4; ++ks)
        wf[ks] = *(const bf16x8*)&Wb[wofs + (size_t)e * 64 + ks * 16 + L * 8];
#pragma unroll
      for (int ks = 0; ks < 4; ++ks)
        acc[nt] = __builtin_amdgcn_mfma_f32_32x32x16_bf16(wf[ks], af[ks], acc[nt], 0, 0, 0);
    }
#pragma unroll
    for (int nt = 0; nt < 2; ++nt)
#pragma unroll
      for (int rq = 0; rq < 4; ++rq) {
        int e0 = nt * 32 + 8 * rq + 4 * L;
        const float* bp = bp0 + h * 64 + e0;
        ushort4 pv;
        pv.x = (unsigned short)bf16rne((acc[nt][4 * rq + 0] + bp[0]) * sc);
        pv.y = (unsigned short)bf16rne((acc[nt][4 * rq + 1] + bp[1]) * sc);
        pv.z = (unsigned short)bf16rne((acc[nt][4 * rq + 2] + bp[2]) * sc);
        pv.w = (unsigned short)bf16rne((acc[nt][4 * rq + 3] + bp[3]) * sc);
        *(ushort4*)&Rt[l31][e0] = pv;    // row = this lane's s_local
      }
    unsigned short* P = (mat == 0) ? Qp : Kp;
#pragma unroll
    for (int p = 0; p < 4; ++p) {
      int f = lane + p * 64;             // 256 x 16B chunks = 4 KB wave tile
      int row = f >> 3, c = f & 7;
      uint4 d = *(const uint4*)&Rt[row][c * 8];
      *(uint4*)&P[((size_t)bh * S_LEN + s0 + wave * 32 + row) * 64 + c * 8] = d;
    }
  }

  // ---- V: acc C[s][e] -> bias -> Vt[e][s] -> coalesced stores ----
  {
    f32x16 vacc[2];
#pragma unroll
    for (int nt = 0; nt < 2; ++nt) {
      const int e = nt * 32 + l31;
      bf16x8 wf[4];
#pragma unroll
      for (int i = 0; i < 16; ++i) vacc[nt][i] = 0.f;
#pragma unroll
      for (int ks = 0; ks < 4; ++ks)
        wf[ks] = *(const bf16x8*)&Wb[2 * 49152 + (size_t)h * 4096 + (size_t)e * 64 + ks * 16 + L * 8];
#pragma unroll
      for (int ks = 0; ks < 4; ++ks)
        vacc[nt] = __builtin_amdgcn_mfma_f32_32x32x16_bf16(af[ks], wf[ks], vacc[nt], 0, 0, 0);
    }
#pragma unroll
    for (int nt = 0; nt < 2; ++nt) {
      const int e = nt * 32 + l31;
      float bias = bv[h * 64 + e];
#pragma unroll
      for (int rq = 0; rq < 4; ++rq) {
        ushort4 pv;
        pv.x = (unsigned short)bf16rne(vacc[nt][4 * rq + 0] + bias);
        pv.y = (unsigned short)bf16rne(vacc[nt][4 * rq + 1] + bias);
        pv.z = (unsigned short)bf16rne(vacc[nt][4 * rq + 2] + bias);
        pv.w = (unsigned short)bf16rne(vacc[nt][4 * rq + 3] + bias);
        *(ushort4*)&Vt[e][8 * rq + 4 * L] = pv;   // s_local = 8rq+4L..+4
      }
    }
#pragma unroll
    for (int p = 0; p < 4; ++p) {
      int f = lane + p * 64;             // 256 x 16B chunks = 4 KB wave tile
      int row = f >> 2, c = f & 3;       // row = e 0..63, c*8 = s_local
      uint4 d = *(const uint4*)&Vt[row][c * 8];
      *(uint4*)&VTp[((size_t)bh * 64 + row) * S_LEN + s0 + wave * 32 + c * 8] = d;
    }
  }
}

// ============ Kernel 2: flash attention, fixed-base softmax ============
// R7 structure (proven -45%): double-buffered K/V LDS, ONE barrier per iter
// with zero outstanding vmem at the barrier. UNCHANGED in R8.
__global__ __launch_bounds__(512)
void flash_attn(const unsigned short* __restrict__ Qp,
                const unsigned short* __restrict__ Kp,
                const unsigned short* __restrict__ VTp,
                float* __restrict__ out) {
  __shared__ __align__(16) char smem[71680];
  unsigned short (*Ks)[128][72]  = (unsigned short(*)[128][72])smem;            // 2x18432 B
  unsigned short (*Vs)[64][136]  = (unsigned short(*)[64][136])(smem + 36864);  // 2x17408 B

  const int tid  = threadIdx.x;
  const int wave = tid >> 6;
  const int lane = tid & 63;
  const int L    = lane >> 5;
  const int l31  = lane & 31;
  const int qw   = wave & 3;    // q-row group
  const int kh   = wave >> 2;   // key half of each tile
  // XCD pinning: id%8 == bh%8 -> all 16 q-tiles of a bh share one XCD's L2
  const int bh = blockIdx.x % NBH;
  const int qx = blockIdx.x / NBH;
  const int b = bh / NHEAD, h = bh % NHEAD;
  const int q0 = qx * BR;

  // Q frags (B-operand): lane holds Q[q=l31][d=ks*16+L*8+j]
  bf16x8 qfrag[4];
  {
    const uint4* Qv = (const uint4*)Qp;
#pragma unroll
    for (int ks = 0; ks < 4; ++ks) {
      B8U t;
      t.u = Qv[((size_t)bh * S_LEN + q0 + qw * 32 + l31) * 8 + ks * 2 + L];
      qfrag[ks] = t.b;
    }
  }

  f32x16 oacc[2];
#pragma unroll
  for (int mt = 0; mt < 2; ++mt)
#pragma unroll
    for (int i = 0; i < 16; ++i) oacc[mt][i] = 0.f;
  float l_run = 0.f;

  const uint4* Kv = (const uint4*)Kp  + (size_t)bh * S_LEN * 8;
  const uint4* Vv = (const uint4*)VTp + (size_t)bh * 64 * 256;

  uint4 kd[2], vd[2];
#pragma unroll
  for (int j = 0; j < 2; ++j) {
    int f = tid + j * 512;
    kd[j] = Kv[(size_t)(f >> 3) * 8 + (f & 7)];
    vd[j] = Vv[(size_t)(f >> 4) * 256 + (f & 15)];
  }

  // EPV: exp2 + bf16-truncate pack + PV-MFMA for one 32-key score tile (tt is
  // the GLOBAL 32-key slot 0..3). l sums the SAME truncated values so rounding
  // bias cancels in p/l.
  int cur = 0;
  auto EPV = [&](const f32x16& sc, int tt) {
    unsigned pk[8];
    float la = 0.f, lb = 0.f;
#pragma unroll
    for (int p = 0; p < 8; ++p) {
      unsigned u0 = __float_as_uint(__builtin_amdgcn_exp2f(sc[2 * p]));
      unsigned u1 = __float_as_uint(__builtin_amdgcn_exp2f(sc[2 * p + 1]));
      unsigned d = __builtin_amdgcn_perm(u1, u0, 0x07060302);  // {hi16(u1),hi16(u0)}
      pk[p] = d;
      la += __uint_as_float(d << 16);
      lb += __uint_as_float(d & 0xffff0000u);
    }
    l_run += la + lb;
#pragma unroll
    for (int mk = 0; mk < 2; ++mk) {
      const int m = 2 * tt + mk;
      unsigned a0 = pk[4 * mk + 0], a1 = pk[4 * mk + 1];
      unsigned b0 = pk[4 * mk + 2], b1 = pk[4 * mk + 3];
      asm("v_permlane32_swap_b32 %0, %1" : "+v"(a0), "+v"(b0));
      asm("v_permlane32_swap_b32 %0, %1" : "+v"(a1), "+v"(b1));
      B8U t;
      t.u.x = a0; t.u.y = a1; t.u.z = b0; t.u.w = b1;
      __builtin_amdgcn_s_setprio(1);
#pragma unroll
      for (int mt = 0; mt < 2; ++mt) {
        bf16x8 va = *(const bf16x8*)&Vs[cur][mt * 32 + l31][m * 16 + L * 8];
        oacc[mt] = __builtin_amdgcn_mfma_f32_32x32x16_bf16(va, t.b, oacc[mt], 0, 0, 0);
      }
      __builtin_amdgcn_s_setprio(0);
    }
  };

  // prologue: stage tile 0 into buf 0
#pragma unroll
  for (int j = 0; j < 2; ++j) {
    int f = tid + j * 512;
    *(uint4*)&Ks[0][f >> 3][(f & 7) * 8]  = kd[j];
    *(uint4*)&Vs[0][f >> 4][(f & 15) * 8] = vd[j];
  }
  __syncthreads();

  for (int i = 0; i < S_LEN / BC; ++i) {
    if (i + 1 < S_LEN / BC) {        // issue next-tile loads; compute covers them
      int t0n = (i + 1) * BC;
#pragma unroll
      for (int j = 0; j < 2; ++j) {
        int f = tid + j * 512;
        kd[j] = Kv[(size_t)(t0n + (f >> 3)) * 8 + (f & 7)];
        vd[j] = Vv[(size_t)(f >> 4) * 256 + (t0n >> 3) + (f & 15)];
      }
    }

    // ---- S^T = K·Q^T for this wave's key half (tiles kh*2, kh*2+1) ----
    f32x16 sacc[2];
#pragma unroll
    for (int tl = 0; tl < 2; ++tl)
#pragma unroll
      for (int j = 0; j < 16; ++j) sacc[tl][j] = 0.f;

    __builtin_amdgcn_s_setprio(1);
#pragma unroll
    for (int ks = 0; ks < 4; ++ks)
#pragma unroll
      for (int tl = 0; tl < 2; ++tl) {
        bf16x8 a = *(const bf16x8*)&Ks[cur][(kh * 2 + tl) * 32 + l31][ks * 16 + L * 8];
        sacc[tl] = __builtin_amdgcn_mfma_f32_32x32x16_bf16(a, qfrag[ks], sacc[tl], 0, 0, 0);
      }
    __builtin_amdgcn_s_setprio(0);

    EPV(sacc[0], kh * 2 + 0);
    EPV(sacc[1], kh * 2 + 1);

    if (i + 1 < S_LEN / BC) {        // stage next tile into the other buffer
#pragma unroll
      for (int j = 0; j < 2; ++j) {
        int f = tid + j * 512;
        *(uint4*)&Ks[cur ^ 1][f >> 3][(f & 7) * 8]  = kd[j];
        *(uint4*)&Vs[cur ^ 1][f >> 4][(f & 15) * 8] = vd[j];
      }
    }
    __syncthreads();                 // single barrier; nothing outstanding
    cur ^= 1;
  }

  l_run += __shfl_xor(l_run, 32, 64);   // q-column's rows split between lane pair

  // ---- merge the two key-half partials (pure sums), then normalize ----
  float* M  = (float*)smem;              // [4 qw][32 q][68 e]  34816 B
  float* Ml = (float*)(smem + 34816);    // [4 qw][32 q] l      512 B
  if (kh == 1) {
    float* Mw = M + qw * (32 * 68);
#pragma unroll
    for (int mt = 0; mt < 2; ++mt)
#pragma unroll
      for (int rq = 0; rq < 4; ++rq) {
        f32x4 v;
        v.x = oacc[mt][4 * rq + 0];
        v.y = oacc[mt][4 * rq + 1];
        v.z = oacc[mt][4 * rq + 2];
        v.w = oacc[mt][4 * rq + 3];
        int e0 = mt * 32 + 8 * rq + 4 * L;
        *(f32x4*)&Mw[l31 * 68 + e0] = v;
      }
    if (lane < 32) Ml[qw * 32 + l31] = l_run;
  }
  __syncthreads();
  if (kh == 0) {
    float* Mw = M + qw * (32 * 68);
#pragma unroll
    for (int mt = 0; mt < 2; ++mt)
#pragma unroll
      for (int rq = 0; rq < 4; ++rq) {
        int e0 = mt * 32 + 8 * rq + 4 * L;
        f32x4 v = *(const f32x4*)&Mw[l31 * 68 + e0];
        oacc[mt][4 * rq + 0] += v.x;
        oacc[mt][4 * rq + 1] += v.y;
        oacc[mt][4 * rq + 2] += v.z;
        oacc[mt][4 * rq + 3] += v.w;
      }
    l_run += Ml[qw * 32 + l31];
  }
  __syncthreads();                       // M dead before Os reuse

  if (kh == 0) {
    float* Os = (float*)smem + qw * (32 * 68);
    float inv = 1.0f / l_run;
#pragma unroll
    for (int mt = 0; mt < 2; ++mt)
#pragma unroll
      for (int rq = 0; rq < 4; ++rq) {
        f32x4 v;
        v.x = oacc[mt][4 * rq + 0] * inv;
        v.y = oacc[mt][4 * rq + 1] * inv;
        v.z = oacc[mt][4 * rq + 2] * inv;
        v.w = oacc[mt][4 * rq + 3] * inv;
        int e0 = mt * 32 + 8 * rq + 4 * L;
        *(f32x4*)&Os[l31 * 68 + e0] = v;
      }
#pragma unroll
    for (int p = 0; p < 8; ++p) {
      int q = (lane >> 4) + 4 * p;
      int e4 = lane & 15;
      float4 t = *(const float4*)&Os[q * 68 + e4 * 4];
      *(float4*)&out[((size_t)(b * S_LEN + q0 + qw * 32 + q)) * DMODEL + h * 64 + e4 * 4] = t;
    }
  }
}

extern "C" void kernel_launch(void* const* d_in, const int* in_sizes, int n_in,
                              void* d_out, int out_size, void* d_ws, size_t ws_size,
                              hipStream_t stream) {
  const float* seq = (const float*)d_in[0];
  const float* Wq  = (const float*)d_in[1];
  const float* Wk  = (const float*)d_in[2];
  const float* Wv  = (const float*)d_in[3];
  const float* bq  = (const float*)d_in[4];
  const float* bk  = (const float*)d_in[5];
  const float* bv  = (const float*)d_in[6];
  float* out = (float*)d_out;

  const size_t wb = 3 * 49152 * sizeof(unsigned short);                // 294912 B
  const size_t qb = (size_t)NBH * S_LEN * 64 * sizeof(unsigned short); // 12.58 MB each
  unsigned short* Wb  = (unsigned short*)d_ws;
  unsigned short* Qp  = (unsigned short*)((char*)d_ws + wb);
  unsigned short* Kp  = (unsigned short*)((char*)d_ws + wb + qb);
  unsigned short* VTp = (unsigned short*)((char*)d_ws + wb + 2 * qb);

  w_cvt<<<dim3(144), 256, 0, stream>>>(Wq, Wk, Wv, Wb);
  qkv_proj<<<dim3(16 * NBH), 256, 0, stream>>>(seq, Wb, bq, bk, bv, Qp, Kp, VTp);
  flash_attn<<<dim3(16 * NBH), 512, 0, stream>>>(Qp, Kp, VTp, out);
}